// Round 10
// baseline (203.338 us; speedup 1.0000x reference)
//
#include <hip/hip_runtime.h>
#include <hip/hip_fp16.h>
#include <stdint.h>

#define N_NODES 100000
#define N_EDGES 1600000
#define N_FEAT 256
#define HIDDEN 128
#define SCAN_CHUNK 1024
#define NB ((N_NODES + SCAN_CHUNK - 1) / SCAN_CHUNK)  // 98

// ---- bucketed CSR build ----
#define BKT_SH 8
#define BKT_RANGE 256                                   // nodes per bucket
#define NBKT ((N_NODES + BKT_RANGE - 1) >> BKT_SH)      // 391
#define BKT_CAP 4608                                    // mean 4096 + 8 sigma
#define BIN_CHUNK 4096
#define NWG_BIN ((N_EDGES + BIN_CHUNK - 1) / BIN_CHUNK) // 391

typedef __attribute__((ext_vector_type(8))) short bf16x8;
typedef __attribute__((ext_vector_type(4))) float f32x4;

// ---------------- zero bucket cursors + h2 sentinel row ----------------

__global__ __launch_bounds__(256) void k_zerog(int* __restrict__ g,
                                               int* __restrict__ h2zero) {
    int i = blockIdx.x * 256 + threadIdx.x;
    if (i < NBKT) g[i] = 0;
    if (blockIdx.x == 0 && threadIdx.x < 64) h2zero[threadIdx.x] = 0;  // 256 B zero row
}

// ---------------- bin edges into target-range buckets ----------------

__global__ __launch_bounds__(256) void k_bin(const int* __restrict__ row,
                                             const int* __restrict__ col,
                                             int* __restrict__ gcur,
                                             int2* __restrict__ recs) {
    __shared__ int hcnt[NBKT];
    __shared__ int hbase[NBKT];
    const int t = threadIdx.x;
    for (int i = t; i < NBKT; i += 256) hcnt[i] = 0;
    __syncthreads();
    const int e0 = blockIdx.x * BIN_CHUNK;
    int cs[16], ss[16];
#pragma unroll
    for (int i = 0; i < 16; ++i) {
        int e = e0 + t + i * 256;
        if (e < N_EDGES) {
            cs[i] = col[e];
            ss[i] = row[e];
            atomicAdd(&hcnt[cs[i] >> BKT_SH], 1);
        } else {
            cs[i] = -1;
        }
    }
    __syncthreads();
    for (int i = t; i < NBKT; i += 256) {
        int c = hcnt[i];
        hbase[i] = (c > 0) ? atomicAdd(&gcur[i], c) : 0;
    }
    __syncthreads();
    for (int i = t; i < NBKT; i += 256) hcnt[i] = 0;  // reuse as local cursor
    __syncthreads();
#pragma unroll
    for (int i = 0; i < 16; ++i) {
        if (cs[i] >= 0) {
            int bkt = cs[i] >> BKT_SH;
            int pos = hbase[bkt] + atomicAdd(&hcnt[bkt], 1);
            if (pos < BKT_CAP)
                recs[(size_t)bkt * BKT_CAP + pos] = make_int2(cs[i], ss[i]);
        }
    }
}

// ---------------- per-bucket degree histogram (+ fused dinv) ----------------

__global__ __launch_bounds__(256) void k_hist(const int* __restrict__ gcur,
                                              const int2* __restrict__ recs,
                                              int* __restrict__ cnt,
                                              float* __restrict__ dinv) {
    __shared__ int hc[BKT_RANGE];
    const int b = blockIdx.x, t = threadIdx.x;
    hc[t] = 0;
    __syncthreads();
    int n = gcur[b];
    if (n > BKT_CAP) n = BKT_CAP;
    const int2* rb = recs + (size_t)b * BKT_CAP;
    for (int i = t; i < n; i += 256)
        atomicAdd(&hc[rb[i].x & (BKT_RANGE - 1)], 1);
    __syncthreads();
    int node = (b << BKT_SH) + t;
    if (node < N_NODES) {
        cnt[node] = hc[t];
        dinv[node] = rsqrtf((float)(hc[t] + 1));  // +1 self-loop
    }
}

// ---------------- exclusive scan of cnt -> row_ptr ----------------

__global__ __launch_bounds__(256) void k_scan1(const int* __restrict__ cnt,
                                               int* __restrict__ row_ptr,
                                               int* __restrict__ bsum) {
    __shared__ int ts[256];
    int t = threadIdx.x;
    int base = blockIdx.x * SCAN_CHUNK + t * 4;
    int v[4];
#pragma unroll
    for (int i = 0; i < 4; ++i) { int idx = base + i; v[i] = (idx < N_NODES) ? cnt[idx] : 0; }
    int s = v[0] + v[1] + v[2] + v[3];
    int val = s;
    ts[t] = val;
    __syncthreads();
    for (int off = 1; off < 256; off <<= 1) {
        int other = (t >= off) ? ts[t - off] : 0;
        __syncthreads();
        val += other;
        ts[t] = val;
        __syncthreads();
    }
    int run = val - s;  // exclusive offset within block
#pragma unroll
    for (int i = 0; i < 4; ++i) {
        int idx = base + i;
        if (idx < N_NODES) row_ptr[idx] = run;
        run += v[i];
    }
    if (t == 255) bsum[blockIdx.x] = val;
}

__global__ void k_scan2(int* __restrict__ bsum, int* __restrict__ row_ptr) {
    if (threadIdx.x == 0) {
        int run = 0;
        for (int i = 0; i < NB; ++i) { int v = bsum[i]; bsum[i] = run; run += v; }
        row_ptr[N_NODES] = run;  // == N_EDGES
    }
}

__global__ __launch_bounds__(256) void k_scan3(int* __restrict__ row_ptr,
                                               const int* __restrict__ bsum) {
    int t = threadIdx.x;
    int base = blockIdx.x * SCAN_CHUNK + t * 4;
    int add = bsum[blockIdx.x];
#pragma unroll
    for (int i = 0; i < 4; ++i) {
        int idx = base + i;
        if (idx < N_NODES) row_ptr[idx] += add;
    }
}

// ---------------- per-bucket scatter into final CSR ----------------

__global__ __launch_bounds__(256) void k_slot2(const int* __restrict__ gcur,
                                               const int2* __restrict__ recs,
                                               const int* __restrict__ row_ptr,
                                               int* __restrict__ edge_src) {
    __shared__ int cur[BKT_RANGE];
    __shared__ int rp[BKT_RANGE];
    const int b = blockIdx.x, t = threadIdx.x;
    cur[t] = 0;
    int node = (b << BKT_SH) + t;
    rp[t] = (node < N_NODES) ? row_ptr[node] : 0;
    __syncthreads();
    int n = gcur[b];
    if (n > BKT_CAP) n = BKT_CAP;
    const int2* rb = recs + (size_t)b * BKT_CAP;
    for (int i = t; i < n; i += 256) {
        int2 r = rb[i];
        int l = r.x & (BKT_RANGE - 1);
        int pos = rp[l] + atomicAdd(&cur[l], 1);
        edge_src[pos] = r.y;
    }
}

// ---------------- W -> bf16 hi/lo (once; 128 KB, L2-hot) ----------------

__global__ __launch_bounds__(256) void k_wconv(const float* __restrict__ W,
                                               short* __restrict__ w_hi,
                                               short* __restrict__ w_lo) {
    int i = blockIdx.x * 256 + threadIdx.x;
    if (i < HIDDEN * N_FEAT) {
        float f = W[i];
        unsigned u = __float_as_uint(f);
        unsigned hb = u & 0xFFFF0000u;           // bf16 truncation
        float r = f - __uint_as_float(hb);       // residual
        w_hi[i] = (short)(u >> 16);
        w_lo[i] = (short)(__float_as_uint(r) >> 16);
    }
}

// ---------------- h2 = fp16(x @ W.T * dinv) via bf16x3 MFMA ----------------
// h = x_hi*W_hi + x_lo*W_hi + x_hi*W_lo (split-precision bf16, fp32 acc).
// Epilogue writes ONLY h2[n] = fp16(h[n]*dinv[n]).  The gather reconstructs
// the self term as dn*h2[n] (sequential read), so no fp32 out base is
// written/read anywhere.
#define TM 128
#define KS 32
#define LDR 40

__global__ __launch_bounds__(256) void k_gemm(const float* __restrict__ x,
                                              const short* __restrict__ w_hi,
                                              const short* __restrict__ w_lo,
                                              const float* __restrict__ dinv,
                                              __half* __restrict__ h2) {
    __shared__ short xh[TM * LDR];
    __shared__ short xl[TM * LDR];
    __shared__ short wh[HIDDEN * LDR];
    __shared__ short wl[HIDDEN * LDR];
    const int t = threadIdx.x;
    const int lane = t & 63;
    const int wv = t >> 6;
    const int wr = wv >> 1, wc = wv & 1;   // 2x2 wave grid
    const int row0 = blockIdx.x * TM;

    f32x4 acc[4][4];
#pragma unroll
    for (int m = 0; m < 4; ++m)
#pragma unroll
        for (int n = 0; n < 4; ++n) acc[m][n] = (f32x4)0.f;

    // staging coords: x tile 128 rows x 32 fp32; thread -> (row, 16-elem half)
    const int rx = t >> 1, sx = t & 1;
    const int gxr = row0 + rx;
    const bool xok = (gxr < N_NODES);

    for (int k0 = 0; k0 < N_FEAT; k0 += KS) {
        // ---- stage x: fp32 -> bf16 hi/lo in registers -> LDS ----
        float4 f[4];
#pragma unroll
        for (int q = 0; q < 4; ++q) {
            f[q] = make_float4(0.f, 0.f, 0.f, 0.f);
            if (xok) f[q] = *(const float4*)&x[(size_t)gxr * N_FEAT + k0 + sx * 16 + q * 4];
        }
        unsigned hp[8], lp[8];
#pragma unroll
        for (int q = 0; q < 4; ++q) {
            float e0 = (&f[q].x)[0], e1 = (&f[q].x)[1], e2 = (&f[q].x)[2], e3 = (&f[q].x)[3];
            unsigned u0 = __float_as_uint(e0), u1 = __float_as_uint(e1);
            unsigned u2 = __float_as_uint(e2), u3 = __float_as_uint(e3);
            unsigned h0 = u0 & 0xFFFF0000u, h1 = u1 & 0xFFFF0000u;
            unsigned h2b = u2 & 0xFFFF0000u, h3 = u3 & 0xFFFF0000u;
            hp[q * 2 + 0] = (u0 >> 16) | h1;
            hp[q * 2 + 1] = (u2 >> 16) | h3;
            float r0 = e0 - __uint_as_float(h0), r1 = e1 - __uint_as_float(h1);
            float r2 = e2 - __uint_as_float(h2b), r3 = e3 - __uint_as_float(h3);
            lp[q * 2 + 0] = (__float_as_uint(r0) >> 16) | (__float_as_uint(r1) & 0xFFFF0000u);
            lp[q * 2 + 1] = (__float_as_uint(r2) >> 16) | (__float_as_uint(r3) & 0xFFFF0000u);
        }
        {
            int o = rx * LDR + sx * 16;  // shorts; 80B rows keep 16B alignment
            *(int4*)&xh[o]     = make_int4(hp[0], hp[1], hp[2], hp[3]);
            *(int4*)&xh[o + 8] = make_int4(hp[4], hp[5], hp[6], hp[7]);
            *(int4*)&xl[o]     = make_int4(lp[0], lp[1], lp[2], lp[3]);
            *(int4*)&xl[o + 8] = make_int4(lp[4], lp[5], lp[6], lp[7]);
        }
        // ---- stage W: bf16 direct copy (global -> reg -> LDS) ----
#pragma unroll
        for (int l = 0; l < 2; ++l) {
            int c = t + 256 * l;
            int rw = c >> 2, sl = c & 3;
            int4 a = *(const int4*)&w_hi[(size_t)rw * N_FEAT + k0 + sl * 8];
            *(int4*)&wh[rw * LDR + sl * 8] = a;
            int4 bq = *(const int4*)&w_lo[(size_t)rw * N_FEAT + k0 + sl * 8];
            *(int4*)&wl[rw * LDR + sl * 8] = bq;
        }
        __syncthreads();
        // ---- fragments ----
        const int fr = lane & 15, fs = lane >> 4;
        bf16x8 ah[4], al[4], bh[4], bl[4];
#pragma unroll
        for (int m = 0; m < 4; ++m) {
            int o = (wr * 64 + m * 16 + fr) * LDR + fs * 8;
            ah[m] = *(const bf16x8*)&xh[o];
            al[m] = *(const bf16x8*)&xl[o];
        }
#pragma unroll
        for (int n = 0; n < 4; ++n) {
            int o = (wc * 64 + n * 16 + fr) * LDR + fs * 8;
            bh[n] = *(const bf16x8*)&wh[o];
            bl[n] = *(const bf16x8*)&wl[o];
        }
        // ---- 3-pass MFMA ----
#pragma unroll
        for (int m = 0; m < 4; ++m)
#pragma unroll
            for (int n = 0; n < 4; ++n) {
                acc[m][n] = __builtin_amdgcn_mfma_f32_16x16x32_bf16(ah[m], bh[n], acc[m][n], 0, 0, 0);
                acc[m][n] = __builtin_amdgcn_mfma_f32_16x16x32_bf16(al[m], bh[n], acc[m][n], 0, 0, 0);
                acc[m][n] = __builtin_amdgcn_mfma_f32_16x16x32_bf16(ah[m], bl[n], acc[m][n], 0, 0, 0);
            }
        __syncthreads();
    }
    // ---- epilogue: h2 = fp16(acc * dinv) only ----
    // C/D layout: col = lane&15, row = (lane>>4)*4 + r
    const int cr = (lane >> 4) * 4, cc = lane & 15;
#pragma unroll
    for (int m = 0; m < 4; ++m) {
        int gr0 = row0 + wr * 64 + m * 16 + cr;
#pragma unroll
        for (int r = 0; r < 4; ++r) {
            int gr = gr0 + r;
            if (gr < N_NODES) {
                float d = dinv[gr];
#pragma unroll
                for (int n = 0; n < 4; ++n) {
                    int gc = wc * 64 + n * 16 + cc;
                    h2[(size_t)gr * HIDDEN + gc] = __float2half_rn(acc[m][n][r] * d);
                }
            }
        }
    }
}

// ---------------- gather-accumulate per node ----------------
// one wave per node; 2 features per lane; batch-16 edge loop, zero-row
// sentinel. Round 10: three source-level MLP attempts failed (compiler
// kept VGPR ~24, loads serialized ~MLP 1-2). Escalate to inline-asm
// global_load_dword x16 (opaque to compiler waitcnt insertion -> issued
// back-to-back) + one asm s_waitcnt vmcnt(0) whose "+v" ties on all 16
// results prevent consumer hoisting (rule #18 pattern). MLP=16 by
// construction.

__global__ __launch_bounds__(256) void k_gather(const int* __restrict__ row_ptr,
                                                const int* __restrict__ edge_src,
                                                const float* __restrict__ dinv,
                                                const __half* __restrict__ h2s,
                                                const float* __restrict__ b,
                                                const float* __restrict__ pa,
                                                float* __restrict__ out) {
    int n = (blockIdx.x * 256 + threadIdx.x) >> 6;
    int lane = threadIdx.x & 63;
    if (n >= N_NODES) return;
    int start = row_ptr[n], end = row_ptr[n + 1];
    float dn = dinv[n];
    // per-lane base into h2: lane covers features [2*lane, 2*lane+1] (4 B)
    const char* hbase = (const char*)h2s + (unsigned)(lane * 4);
    // self term (sequential read of own row)
    float2 acc = __half22float2(*(const __half2*)(hbase + (size_t)(unsigned)n * 256u));
    for (int e = start; e < end; e += 16) {
        int idx[16];
#pragma unroll
        for (int i = 0; i < 16; ++i) {
            int ee = e + i;
            idx[i] = (ee < end) ? edge_src[ee] : N_NODES;  // sentinel -> zero row
        }
        unsigned v[16];
        // 16 gathers issued back-to-back; compiler cannot insert waits it
        // doesn't know about (loads are opaque inside asm).
#pragma unroll
        for (int i = 0; i < 16; ++i) {
            const char* addr = hbase + ((unsigned)idx[i] << 8);  // idx*256
            asm volatile("global_load_dword %0, %1, off"
                         : "=v"(v[i])
                         : "v"(addr));
        }
        // single drain; "+v" ties make every consumer data-depend on this asm
        asm volatile("s_waitcnt vmcnt(0)"
                     : "+v"(v[0]), "+v"(v[1]), "+v"(v[2]), "+v"(v[3]),
                       "+v"(v[4]), "+v"(v[5]), "+v"(v[6]), "+v"(v[7]),
                       "+v"(v[8]), "+v"(v[9]), "+v"(v[10]), "+v"(v[11]),
                       "+v"(v[12]), "+v"(v[13]), "+v"(v[14]), "+v"(v[15]));
        // pairwise tree accumulate (chain depth ~5)
        float2 s[8];
#pragma unroll
        for (int i = 0; i < 8; ++i) {
            float2 a0 = __half22float2(*(const __half2*)&v[2 * i]);
            float2 a1 = __half22float2(*(const __half2*)&v[2 * i + 1]);
            s[i].x = a0.x + a1.x;
            s[i].y = a0.y + a1.y;
        }
#pragma unroll
        for (int i = 0; i < 4; ++i) {
            s[i].x = s[i].x + s[i + 4].x;
            s[i].y = s[i].y + s[i + 4].y;
        }
        s[0].x += s[2].x; s[0].y += s[2].y;
        s[1].x += s[3].x; s[1].y += s[3].y;
        acc.x += s[0].x + s[1].x;
        acc.y += s[0].y + s[1].y;
    }
    float2 bb = *(const float2*)&b[lane * 2];
    float2 r;
    r.x = dn * acc.x + bb.x;
    r.y = dn * acc.y + bb.y;
    float2 aa = *(const float2*)&pa[lane * 2];
    r.x = r.x > 0.f ? r.x : r.x * aa.x;
    r.y = r.y > 0.f ? r.y : r.y * aa.y;
    *(float2*)&out[(size_t)n * HIDDEN + lane * 2] = r;
}

// ---------------- launch ----------------

extern "C" void kernel_launch(void* const* d_in, const int* in_sizes, int n_in,
                              void* d_out, int out_size, void* d_ws, size_t ws_size,
                              hipStream_t stream) {
    const float* x  = (const float*)d_in[0];
    const int*   ei = (const int*)d_in[1];   // [2, E] int32
    const float* W  = (const float*)d_in[2];
    const float* b  = (const float*)d_in[3];
    const float* pa = (const float*)d_in[4];
    float* out = (float*)d_out;

    const int* row = ei;            // sources
    const int* col = ei + N_EDGES;  // targets

    // ---- workspace layout (≈48 MB) ----
    char* w = (char*)d_ws;
    __half* h2      = (__half*)w;                                  // (N+1)*128*2 = 25.6 MB + 256 B
    int*   cnt      = (int*)(w + (size_t)(N_NODES + 1) * HIDDEN * 2);  // 400 KB
    int*   row_ptr  = cnt + N_NODES;                               // 400 KB + 8
    int*   bsum     = row_ptr + (N_NODES + 2);                     // 512 B
    int*   edge_src = bsum + 128;                                  // 6.4 MB
    float* dinv     = (float*)(edge_src + N_EDGES);                // 400 KB
    short* w_hi     = (short*)(dinv + N_NODES);                    // 64 KB
    short* w_lo     = w_hi + HIDDEN * N_FEAT;                      // 64 KB
    int*   gcur     = (int*)(w_lo + HIDDEN * N_FEAT);              // 1.6 KB
    int2*  recs     = (int2*)(((uintptr_t)(gcur + NBKT) + 15) & ~(uintptr_t)15);  // 14.4 MB

    int* h2zero = (int*)(h2 + (size_t)N_NODES * HIDDEN);  // sentinel row

    k_zerog<<<(NBKT + 255) / 256, 256, 0, stream>>>(gcur, h2zero);
    k_bin<<<NWG_BIN, 256, 0, stream>>>(row, col, gcur, recs);
    k_hist<<<NBKT, 256, 0, stream>>>(gcur, recs, cnt, dinv);
    k_scan1<<<NB, 256, 0, stream>>>(cnt, row_ptr, bsum);
    k_scan2<<<1, 64, 0, stream>>>(bsum, row_ptr);
    k_scan3<<<NB, 256, 0, stream>>>(row_ptr, bsum);
    k_slot2<<<NBKT, 256, 0, stream>>>(gcur, recs, row_ptr, edge_src);
    k_wconv<<<(HIDDEN * N_FEAT + 255) / 256, 256, 0, stream>>>(W, w_hi, w_lo);
    k_gemm<<<(N_NODES + TM - 1) / TM, 256, 0, stream>>>(x, w_hi, w_lo, dinv, h2);
    k_gather<<<(int)(((size_t)N_NODES * 64 + 255) / 256), 256, 0, stream>>>(
        row_ptr, edge_src, dinv, h2, b, pa, out);
}

// Round 11
// 201.891 us; speedup vs baseline: 1.0072x; 1.0072x over previous
//
#include <hip/hip_runtime.h>
#include <hip/hip_fp16.h>
#include <stdint.h>

#define N_NODES 100000
#define N_EDGES 1600000
#define N_FEAT 256
#define HIDDEN 128
#define SCAN_CHUNK 1024
#define NB ((N_NODES + SCAN_CHUNK - 1) / SCAN_CHUNK)  // 98

// ---- bucketed CSR build ----
#define BKT_SH 8
#define BKT_RANGE 256                                   // nodes per bucket
#define NBKT ((N_NODES + BKT_RANGE - 1) >> BKT_SH)      // 391
#define BKT_CAP 4608                                    // mean 4096 + 8 sigma
#define BIN_CHUNK 4096
#define NWG_BIN ((N_EDGES + BIN_CHUNK - 1) / BIN_CHUNK) // 391

typedef __attribute__((ext_vector_type(8))) short bf16x8;
typedef __attribute__((ext_vector_type(4))) float f32x4;

// ---------------- zero bucket cursors + h2 sentinel row ----------------

__global__ __launch_bounds__(256) void k_zerog(int* __restrict__ g,
                                               int* __restrict__ h2zero) {
    int i = blockIdx.x * 256 + threadIdx.x;
    if (i < NBKT) g[i] = 0;
    if (blockIdx.x == 0 && threadIdx.x < 64) h2zero[threadIdx.x] = 0;  // 256 B zero row
}

// ---------------- bin edges into target-range buckets ----------------

__global__ __launch_bounds__(256) void k_bin(const int* __restrict__ row,
                                             const int* __restrict__ col,
                                             int* __restrict__ gcur,
                                             int2* __restrict__ recs) {
    __shared__ int hcnt[NBKT];
    __shared__ int hbase[NBKT];
    const int t = threadIdx.x;
    for (int i = t; i < NBKT; i += 256) hcnt[i] = 0;
    __syncthreads();
    const int e0 = blockIdx.x * BIN_CHUNK;
    int cs[16], ss[16];
#pragma unroll
    for (int i = 0; i < 16; ++i) {
        int e = e0 + t + i * 256;
        if (e < N_EDGES) {
            cs[i] = col[e];
            ss[i] = row[e];
            atomicAdd(&hcnt[cs[i] >> BKT_SH], 1);
        } else {
            cs[i] = -1;
        }
    }
    __syncthreads();
    for (int i = t; i < NBKT; i += 256) {
        int c = hcnt[i];
        hbase[i] = (c > 0) ? atomicAdd(&gcur[i], c) : 0;
    }
    __syncthreads();
    for (int i = t; i < NBKT; i += 256) hcnt[i] = 0;  // reuse as local cursor
    __syncthreads();
#pragma unroll
    for (int i = 0; i < 16; ++i) {
        if (cs[i] >= 0) {
            int bkt = cs[i] >> BKT_SH;
            int pos = hbase[bkt] + atomicAdd(&hcnt[bkt], 1);
            if (pos < BKT_CAP)
                recs[(size_t)bkt * BKT_CAP + pos] = make_int2(cs[i], ss[i]);
        }
    }
}

// ---------------- per-bucket degree histogram (+ fused dinv) ----------------

__global__ __launch_bounds__(256) void k_hist(const int* __restrict__ gcur,
                                              const int2* __restrict__ recs,
                                              int* __restrict__ cnt,
                                              float* __restrict__ dinv) {
    __shared__ int hc[BKT_RANGE];
    const int b = blockIdx.x, t = threadIdx.x;
    hc[t] = 0;
    __syncthreads();
    int n = gcur[b];
    if (n > BKT_CAP) n = BKT_CAP;
    const int2* rb = recs + (size_t)b * BKT_CAP;
    for (int i = t; i < n; i += 256)
        atomicAdd(&hc[rb[i].x & (BKT_RANGE - 1)], 1);
    __syncthreads();
    int node = (b << BKT_SH) + t;
    if (node < N_NODES) {
        cnt[node] = hc[t];
        dinv[node] = rsqrtf((float)(hc[t] + 1));  // +1 self-loop
    }
}

// ---------------- exclusive scan of cnt -> row_ptr ----------------

__global__ __launch_bounds__(256) void k_scan1(const int* __restrict__ cnt,
                                               int* __restrict__ row_ptr,
                                               int* __restrict__ bsum) {
    __shared__ int ts[256];
    int t = threadIdx.x;
    int base = blockIdx.x * SCAN_CHUNK + t * 4;
    int v[4];
#pragma unroll
    for (int i = 0; i < 4; ++i) { int idx = base + i; v[i] = (idx < N_NODES) ? cnt[idx] : 0; }
    int s = v[0] + v[1] + v[2] + v[3];
    int val = s;
    ts[t] = val;
    __syncthreads();
    for (int off = 1; off < 256; off <<= 1) {
        int other = (t >= off) ? ts[t - off] : 0;
        __syncthreads();
        val += other;
        ts[t] = val;
        __syncthreads();
    }
    int run = val - s;  // exclusive offset within block
#pragma unroll
    for (int i = 0; i < 4; ++i) {
        int idx = base + i;
        if (idx < N_NODES) row_ptr[idx] = run;
        run += v[i];
    }
    if (t == 255) bsum[blockIdx.x] = val;
}

__global__ void k_scan2(int* __restrict__ bsum, int* __restrict__ row_ptr) {
    if (threadIdx.x == 0) {
        int run = 0;
        for (int i = 0; i < NB; ++i) { int v = bsum[i]; bsum[i] = run; run += v; }
        row_ptr[N_NODES] = run;  // == N_EDGES
    }
}

__global__ __launch_bounds__(256) void k_scan3(int* __restrict__ row_ptr,
                                               const int* __restrict__ bsum) {
    int t = threadIdx.x;
    int base = blockIdx.x * SCAN_CHUNK + t * 4;
    int add = bsum[blockIdx.x];
#pragma unroll
    for (int i = 0; i < 4; ++i) {
        int idx = base + i;
        if (idx < N_NODES) row_ptr[idx] += add;
    }
}

// ---------------- per-bucket scatter into final CSR ----------------

__global__ __launch_bounds__(256) void k_slot2(const int* __restrict__ gcur,
                                               const int2* __restrict__ recs,
                                               const int* __restrict__ row_ptr,
                                               int* __restrict__ edge_src) {
    __shared__ int cur[BKT_RANGE];
    __shared__ int rp[BKT_RANGE];
    const int b = blockIdx.x, t = threadIdx.x;
    cur[t] = 0;
    int node = (b << BKT_SH) + t;
    rp[t] = (node < N_NODES) ? row_ptr[node] : 0;
    __syncthreads();
    int n = gcur[b];
    if (n > BKT_CAP) n = BKT_CAP;
    const int2* rb = recs + (size_t)b * BKT_CAP;
    for (int i = t; i < n; i += 256) {
        int2 r = rb[i];
        int l = r.x & (BKT_RANGE - 1);
        int pos = rp[l] + atomicAdd(&cur[l], 1);
        edge_src[pos] = r.y;
    }
}

// ---------------- W -> bf16 hi/lo (once; 128 KB, L2-hot) ----------------

__global__ __launch_bounds__(256) void k_wconv(const float* __restrict__ W,
                                               short* __restrict__ w_hi,
                                               short* __restrict__ w_lo) {
    int i = blockIdx.x * 256 + threadIdx.x;
    if (i < HIDDEN * N_FEAT) {
        float f = W[i];
        unsigned u = __float_as_uint(f);
        unsigned hb = u & 0xFFFF0000u;           // bf16 truncation
        float r = f - __uint_as_float(hb);       // residual
        w_hi[i] = (short)(u >> 16);
        w_lo[i] = (short)(__float_as_uint(r) >> 16);
    }
}

// ---------------- h2 = fp16(x @ W.T * dinv) via bf16x3 MFMA ----------------
// h = x_hi*W_hi + x_lo*W_hi + x_hi*W_lo (split-precision bf16, fp32 acc).
// Epilogue writes ONLY h2[n] = fp16(h[n]*dinv[n]).  The gather reconstructs
// the self term as dn*h2[n] (sequential read), so no fp32 out base is
// written/read anywhere.
#define TM 128
#define KS 32
#define LDR 40

__global__ __launch_bounds__(256) void k_gemm(const float* __restrict__ x,
                                              const short* __restrict__ w_hi,
                                              const short* __restrict__ w_lo,
                                              const float* __restrict__ dinv,
                                              __half* __restrict__ h2) {
    __shared__ short xh[TM * LDR];
    __shared__ short xl[TM * LDR];
    __shared__ short wh[HIDDEN * LDR];
    __shared__ short wl[HIDDEN * LDR];
    const int t = threadIdx.x;
    const int lane = t & 63;
    const int wv = t >> 6;
    const int wr = wv >> 1, wc = wv & 1;   // 2x2 wave grid
    const int row0 = blockIdx.x * TM;

    f32x4 acc[4][4];
#pragma unroll
    for (int m = 0; m < 4; ++m)
#pragma unroll
        for (int n = 0; n < 4; ++n) acc[m][n] = (f32x4)0.f;

    // staging coords: x tile 128 rows x 32 fp32; thread -> (row, 16-elem half)
    const int rx = t >> 1, sx = t & 1;
    const int gxr = row0 + rx;
    const bool xok = (gxr < N_NODES);

    for (int k0 = 0; k0 < N_FEAT; k0 += KS) {
        // ---- stage x: fp32 -> bf16 hi/lo in registers -> LDS ----
        float4 f[4];
#pragma unroll
        for (int q = 0; q < 4; ++q) {
            f[q] = make_float4(0.f, 0.f, 0.f, 0.f);
            if (xok) f[q] = *(const float4*)&x[(size_t)gxr * N_FEAT + k0 + sx * 16 + q * 4];
        }
        unsigned hp[8], lp[8];
#pragma unroll
        for (int q = 0; q < 4; ++q) {
            float e0 = (&f[q].x)[0], e1 = (&f[q].x)[1], e2 = (&f[q].x)[2], e3 = (&f[q].x)[3];
            unsigned u0 = __float_as_uint(e0), u1 = __float_as_uint(e1);
            unsigned u2 = __float_as_uint(e2), u3 = __float_as_uint(e3);
            unsigned h0 = u0 & 0xFFFF0000u, h1 = u1 & 0xFFFF0000u;
            unsigned h2b = u2 & 0xFFFF0000u, h3 = u3 & 0xFFFF0000u;
            hp[q * 2 + 0] = (u0 >> 16) | h1;
            hp[q * 2 + 1] = (u2 >> 16) | h3;
            float r0 = e0 - __uint_as_float(h0), r1 = e1 - __uint_as_float(h1);
            float r2 = e2 - __uint_as_float(h2b), r3 = e3 - __uint_as_float(h3);
            lp[q * 2 + 0] = (__float_as_uint(r0) >> 16) | (__float_as_uint(r1) & 0xFFFF0000u);
            lp[q * 2 + 1] = (__float_as_uint(r2) >> 16) | (__float_as_uint(r3) & 0xFFFF0000u);
        }
        {
            int o = rx * LDR + sx * 16;  // shorts; 80B rows keep 16B alignment
            *(int4*)&xh[o]     = make_int4(hp[0], hp[1], hp[2], hp[3]);
            *(int4*)&xh[o + 8] = make_int4(hp[4], hp[5], hp[6], hp[7]);
            *(int4*)&xl[o]     = make_int4(lp[0], lp[1], lp[2], lp[3]);
            *(int4*)&xl[o + 8] = make_int4(lp[4], lp[5], lp[6], lp[7]);
        }
        // ---- stage W: bf16 direct copy (global -> reg -> LDS) ----
#pragma unroll
        for (int l = 0; l < 2; ++l) {
            int c = t + 256 * l;
            int rw = c >> 2, sl = c & 3;
            int4 a = *(const int4*)&w_hi[(size_t)rw * N_FEAT + k0 + sl * 8];
            *(int4*)&wh[rw * LDR + sl * 8] = a;
            int4 bq = *(const int4*)&w_lo[(size_t)rw * N_FEAT + k0 + sl * 8];
            *(int4*)&wl[rw * LDR + sl * 8] = bq;
        }
        __syncthreads();
        // ---- fragments ----
        const int fr = lane & 15, fs = lane >> 4;
        bf16x8 ah[4], al[4], bh[4], bl[4];
#pragma unroll
        for (int m = 0; m < 4; ++m) {
            int o = (wr * 64 + m * 16 + fr) * LDR + fs * 8;
            ah[m] = *(const bf16x8*)&xh[o];
            al[m] = *(const bf16x8*)&xl[o];
        }
#pragma unroll
        for (int n = 0; n < 4; ++n) {
            int o = (wc * 64 + n * 16 + fr) * LDR + fs * 8;
            bh[n] = *(const bf16x8*)&wh[o];
            bl[n] = *(const bf16x8*)&wl[o];
        }
        // ---- 3-pass MFMA ----
#pragma unroll
        for (int m = 0; m < 4; ++m)
#pragma unroll
            for (int n = 0; n < 4; ++n) {
                acc[m][n] = __builtin_amdgcn_mfma_f32_16x16x32_bf16(ah[m], bh[n], acc[m][n], 0, 0, 0);
                acc[m][n] = __builtin_amdgcn_mfma_f32_16x16x32_bf16(al[m], bh[n], acc[m][n], 0, 0, 0);
                acc[m][n] = __builtin_amdgcn_mfma_f32_16x16x32_bf16(ah[m], bl[n], acc[m][n], 0, 0, 0);
            }
        __syncthreads();
    }
    // ---- epilogue: h2 = fp16(acc * dinv) only ----
    // C/D layout: col = lane&15, row = (lane>>4)*4 + r
    const int cr = (lane >> 4) * 4, cc = lane & 15;
#pragma unroll
    for (int m = 0; m < 4; ++m) {
        int gr0 = row0 + wr * 64 + m * 16 + cr;
#pragma unroll
        for (int r = 0; r < 4; ++r) {
            int gr = gr0 + r;
            if (gr < N_NODES) {
                float d = dinv[gr];
#pragma unroll
                for (int n = 0; n < 4; ++n) {
                    int gc = wc * 64 + n * 16 + cc;
                    h2[(size_t)gr * HIDDEN + gc] = __float2half_rn(acc[m][n][r] * d);
                }
            }
        }
    }
}

// ---------------- gather-accumulate per node ----------------
// Round 11: round 10's serialization diagnosed -- compiler-issued edge_src
// loads interleaved with asm gathers forced per-gather vmcnt(0) (the idx
// wait drains the whole queue). Fix: PRECOMPUTE all 16 32-bit voffsets
// (idx waits land here), sched_barrier, then 16 back-to-back SGPR-base
// gathers with no compiler memory ops in between, one vmcnt(0) drain.

__global__ __launch_bounds__(256) void k_gather(const int* __restrict__ row_ptr,
                                                const int* __restrict__ edge_src,
                                                const float* __restrict__ dinv,
                                                const __half* __restrict__ h2s,
                                                const float* __restrict__ b,
                                                const float* __restrict__ pa,
                                                float* __restrict__ out) {
    int n = (blockIdx.x * 256 + threadIdx.x) >> 6;
    int lane = threadIdx.x & 63;
    if (n >= N_NODES) return;
    int start = row_ptr[n], end = row_ptr[n + 1];
    float dn = dinv[n];
    const unsigned loff = (unsigned)(lane * 4);
    unsigned long long sbase = (unsigned long long)(const void*)h2s;
    // self term (sequential read of own row)
    float2 acc = __half22float2(
        *(const __half2*)((const char*)h2s + (size_t)(unsigned)n * 256u + loff));
    for (int e = start; e < end; e += 16) {
        // phase 1: resolve all indices -> 32-bit voffsets (compiler waits here)
        unsigned voff[16];
#pragma unroll
        for (int i = 0; i < 16; ++i) {
            int ee = e + i;
            int id = (ee < end) ? edge_src[ee] : N_NODES;  // sentinel -> zero row
            voff[i] = ((unsigned)id << 8) + loff;
        }
        __builtin_amdgcn_sched_barrier(0);  // keep phase 1 out of the burst
        // phase 2: 16 gathers back-to-back (SGPR base + voffset); no compiler
        // memory ops in between -> no compiler waitcnt can split the burst.
        unsigned v[16];
#pragma unroll
        for (int i = 0; i < 16; ++i) {
            asm volatile("global_load_dword %0, %1, %2"
                         : "=v"(v[i])
                         : "v"(voff[i]), "s"(sbase));
        }
        // phase 3: single drain; "+v" ties prevent consumer hoisting
        asm volatile("s_waitcnt vmcnt(0)"
                     : "+v"(v[0]), "+v"(v[1]), "+v"(v[2]), "+v"(v[3]),
                       "+v"(v[4]), "+v"(v[5]), "+v"(v[6]), "+v"(v[7]),
                       "+v"(v[8]), "+v"(v[9]), "+v"(v[10]), "+v"(v[11]),
                       "+v"(v[12]), "+v"(v[13]), "+v"(v[14]), "+v"(v[15]));
        // pairwise tree accumulate (chain depth ~5)
        float2 s[8];
#pragma unroll
        for (int i = 0; i < 8; ++i) {
            float2 a0 = __half22float2(*(const __half2*)&v[2 * i]);
            float2 a1 = __half22float2(*(const __half2*)&v[2 * i + 1]);
            s[i].x = a0.x + a1.x;
            s[i].y = a0.y + a1.y;
        }
#pragma unroll
        for (int i = 0; i < 4; ++i) {
            s[i].x = s[i].x + s[i + 4].x;
            s[i].y = s[i].y + s[i + 4].y;
        }
        s[0].x += s[2].x; s[0].y += s[2].y;
        s[1].x += s[3].x; s[1].y += s[3].y;
        acc.x += s[0].x + s[1].x;
        acc.y += s[0].y + s[1].y;
    }
    float2 bb = *(const float2*)&b[lane * 2];
    float2 r;
    r.x = dn * acc.x + bb.x;
    r.y = dn * acc.y + bb.y;
    float2 aa = *(const float2*)&pa[lane * 2];
    r.x = r.x > 0.f ? r.x : r.x * aa.x;
    r.y = r.y > 0.f ? r.y : r.y * aa.y;
    *(float2*)&out[(size_t)n * HIDDEN + lane * 2] = r;
}

// ---------------- launch ----------------

extern "C" void kernel_launch(void* const* d_in, const int* in_sizes, int n_in,
                              void* d_out, int out_size, void* d_ws, size_t ws_size,
                              hipStream_t stream) {
    const float* x  = (const float*)d_in[0];
    const int*   ei = (const int*)d_in[1];   // [2, E] int32
    const float* W  = (const float*)d_in[2];
    const float* b  = (const float*)d_in[3];
    const float* pa = (const float*)d_in[4];
    float* out = (float*)d_out;

    const int* row = ei;            // sources
    const int* col = ei + N_EDGES;  // targets

    // ---- workspace layout (≈48 MB) ----
    char* w = (char*)d_ws;
    __half* h2      = (__half*)w;                                  // (N+1)*128*2 = 25.6 MB + 256 B
    int*   cnt      = (int*)(w + (size_t)(N_NODES + 1) * HIDDEN * 2);  // 400 KB
    int*   row_ptr  = cnt + N_NODES;                               // 400 KB + 8
    int*   bsum     = row_ptr + (N_NODES + 2);                     // 512 B
    int*   edge_src = bsum + 128;                                  // 6.4 MB
    float* dinv     = (float*)(edge_src + N_EDGES);                // 400 KB
    short* w_hi     = (short*)(dinv + N_NODES);                    // 64 KB
    short* w_lo     = w_hi + HIDDEN * N_FEAT;                      // 64 KB
    int*   gcur     = (int*)(w_lo + HIDDEN * N_FEAT);              // 1.6 KB
    int2*  recs     = (int2*)(((uintptr_t)(gcur + NBKT) + 15) & ~(uintptr_t)15);  // 14.4 MB

    int* h2zero = (int*)(h2 + (size_t)N_NODES * HIDDEN);  // sentinel row

    k_zerog<<<(NBKT + 255) / 256, 256, 0, stream>>>(gcur, h2zero);
    k_bin<<<NWG_BIN, 256, 0, stream>>>(row, col, gcur, recs);
    k_hist<<<NBKT, 256, 0, stream>>>(gcur, recs, cnt, dinv);
    k_scan1<<<NB, 256, 0, stream>>>(cnt, row_ptr, bsum);
    k_scan2<<<1, 64, 0, stream>>>(bsum, row_ptr);
    k_scan3<<<NB, 256, 0, stream>>>(row_ptr, bsum);
    k_slot2<<<NBKT, 256, 0, stream>>>(gcur, recs, row_ptr, edge_src);
    k_wconv<<<(HIDDEN * N_FEAT + 255) / 256, 256, 0, stream>>>(W, w_hi, w_lo);
    k_gemm<<<(N_NODES + TM - 1) / TM, 256, 0, stream>>>(x, w_hi, w_lo, dinv, h2);
    k_gather<<<(int)(((size_t)N_NODES * 64 + 255) / 256), 256, 0, stream>>>(
        row_ptr, edge_src, dinv, h2, b, pa, out);
}

// Round 12
// 172.371 us; speedup vs baseline: 1.1797x; 1.1713x over previous
//
#include <hip/hip_runtime.h>
#include <hip/hip_fp16.h>
#include <stdint.h>

#define N_NODES 100000
#define N_EDGES 1600000
#define N_FEAT 256
#define HIDDEN 128
#define SCAN_CHUNK 1024
#define NB ((N_NODES + SCAN_CHUNK - 1) / SCAN_CHUNK)  // 98

// ---- bucketed CSR build ----
#define BKT_SH 8
#define BKT_RANGE 256                                   // nodes per bucket
#define NBKT ((N_NODES + BKT_RANGE - 1) >> BKT_SH)      // 391
#define BKT_CAP 4608                                    // mean 4096 + 8 sigma
#define BIN_CHUNK 4096
#define NWG_BIN ((N_EDGES + BIN_CHUNK - 1) / BIN_CHUNK) // 391

typedef __attribute__((ext_vector_type(8))) short bf16x8;
typedef __attribute__((ext_vector_type(4))) float f32x4;

// ---------------- zero bucket cursors ----------------

__global__ __launch_bounds__(256) void k_zerog(int* __restrict__ g) {
    int i = blockIdx.x * 256 + threadIdx.x;
    if (i < NBKT) g[i] = 0;
}

// ---------------- bin edges into target-range buckets ----------------

__global__ __launch_bounds__(256) void k_bin(const int* __restrict__ row,
                                             const int* __restrict__ col,
                                             int* __restrict__ gcur,
                                             int2* __restrict__ recs) {
    __shared__ int hcnt[NBKT];
    __shared__ int hbase[NBKT];
    const int t = threadIdx.x;
    for (int i = t; i < NBKT; i += 256) hcnt[i] = 0;
    __syncthreads();
    const int e0 = blockIdx.x * BIN_CHUNK;
    int cs[16], ss[16];
#pragma unroll
    for (int i = 0; i < 16; ++i) {
        int e = e0 + t + i * 256;
        if (e < N_EDGES) {
            cs[i] = col[e];
            ss[i] = row[e];
            atomicAdd(&hcnt[cs[i] >> BKT_SH], 1);
        } else {
            cs[i] = -1;
        }
    }
    __syncthreads();
    for (int i = t; i < NBKT; i += 256) {
        int c = hcnt[i];
        hbase[i] = (c > 0) ? atomicAdd(&gcur[i], c) : 0;
    }
    __syncthreads();
    for (int i = t; i < NBKT; i += 256) hcnt[i] = 0;  // reuse as local cursor
    __syncthreads();
#pragma unroll
    for (int i = 0; i < 16; ++i) {
        if (cs[i] >= 0) {
            int bkt = cs[i] >> BKT_SH;
            int pos = hbase[bkt] + atomicAdd(&hcnt[bkt], 1);
            if (pos < BKT_CAP)
                recs[(size_t)bkt * BKT_CAP + pos] = make_int2(cs[i], ss[i]);
        }
    }
}

// ---------------- per-bucket degree histogram (+ fused dinv) ----------------

__global__ __launch_bounds__(256) void k_hist(const int* __restrict__ gcur,
                                              const int2* __restrict__ recs,
                                              int* __restrict__ cnt,
                                              float* __restrict__ dinv) {
    __shared__ int hc[BKT_RANGE];
    const int b = blockIdx.x, t = threadIdx.x;
    hc[t] = 0;
    __syncthreads();
    int n = gcur[b];
    if (n > BKT_CAP) n = BKT_CAP;
    const int2* rb = recs + (size_t)b * BKT_CAP;
    for (int i = t; i < n; i += 256)
        atomicAdd(&hc[rb[i].x & (BKT_RANGE - 1)], 1);
    __syncthreads();
    int node = (b << BKT_SH) + t;
    if (node < N_NODES) {
        cnt[node] = hc[t];
        dinv[node] = rsqrtf((float)(hc[t] + 1));  // +1 self-loop
    }
}

// ---------------- exclusive scan of cnt -> row_ptr ----------------

__global__ __launch_bounds__(256) void k_scan1(const int* __restrict__ cnt,
                                               int* __restrict__ row_ptr,
                                               int* __restrict__ bsum) {
    __shared__ int ts[256];
    int t = threadIdx.x;
    int base = blockIdx.x * SCAN_CHUNK + t * 4;
    int v[4];
#pragma unroll
    for (int i = 0; i < 4; ++i) { int idx = base + i; v[i] = (idx < N_NODES) ? cnt[idx] : 0; }
    int s = v[0] + v[1] + v[2] + v[3];
    int val = s;
    ts[t] = val;
    __syncthreads();
    for (int off = 1; off < 256; off <<= 1) {
        int other = (t >= off) ? ts[t - off] : 0;
        __syncthreads();
        val += other;
        ts[t] = val;
        __syncthreads();
    }
    int run = val - s;  // exclusive offset within block
#pragma unroll
    for (int i = 0; i < 4; ++i) {
        int idx = base + i;
        if (idx < N_NODES) row_ptr[idx] = run;
        run += v[i];
    }
    if (t == 255) bsum[blockIdx.x] = val;
}

__global__ void k_scan2(int* __restrict__ bsum, int* __restrict__ row_ptr) {
    if (threadIdx.x == 0) {
        int run = 0;
        for (int i = 0; i < NB; ++i) { int v = bsum[i]; bsum[i] = run; run += v; }
        row_ptr[N_NODES] = run;  // == N_EDGES
    }
}

__global__ __launch_bounds__(256) void k_scan3(int* __restrict__ row_ptr,
                                               const int* __restrict__ bsum) {
    int t = threadIdx.x;
    int base = blockIdx.x * SCAN_CHUNK + t * 4;
    int add = bsum[blockIdx.x];
#pragma unroll
    for (int i = 0; i < 4; ++i) {
        int idx = base + i;
        if (idx < N_NODES) row_ptr[idx] += add;
    }
}

// ---------------- per-bucket scatter into final CSR ----------------

__global__ __launch_bounds__(256) void k_slot2(const int* __restrict__ gcur,
                                               const int2* __restrict__ recs,
                                               const int* __restrict__ row_ptr,
                                               int* __restrict__ edge_src) {
    __shared__ int cur[BKT_RANGE];
    __shared__ int rp[BKT_RANGE];
    const int b = blockIdx.x, t = threadIdx.x;
    cur[t] = 0;
    int node = (b << BKT_SH) + t;
    rp[t] = (node < N_NODES) ? row_ptr[node] : 0;
    __syncthreads();
    int n = gcur[b];
    if (n > BKT_CAP) n = BKT_CAP;
    const int2* rb = recs + (size_t)b * BKT_CAP;
    for (int i = t; i < n; i += 256) {
        int2 r = rb[i];
        int l = r.x & (BKT_RANGE - 1);
        int pos = rp[l] + atomicAdd(&cur[l], 1);
        edge_src[pos] = r.y;
    }
}

// ---------------- W -> bf16 hi/lo (once; 128 KB, L2-hot) ----------------

__global__ __launch_bounds__(256) void k_wconv(const float* __restrict__ W,
                                               short* __restrict__ w_hi,
                                               short* __restrict__ w_lo) {
    int i = blockIdx.x * 256 + threadIdx.x;
    if (i < HIDDEN * N_FEAT) {
        float f = W[i];
        unsigned u = __float_as_uint(f);
        unsigned hb = u & 0xFFFF0000u;           // bf16 truncation
        float r = f - __uint_as_float(hb);       // residual
        w_hi[i] = (short)(u >> 16);
        w_lo[i] = (short)(__float_as_uint(r) >> 16);
    }
}

// ---------------- h2 = fp16(x @ W.T * dinv) via bf16x3 MFMA ----------------
// h = x_hi*W_hi + x_lo*W_hi + x_hi*W_lo (split-precision bf16, fp32 acc).
// Epilogue writes ONLY h2[n] = fp16(h[n]*dinv[n]); the gather reconstructs
// the self term from h2[n] (sequential read) -> out is write-only.
#define TM 128
#define KS 32
#define LDR 40

__global__ __launch_bounds__(256) void k_gemm(const float* __restrict__ x,
                                              const short* __restrict__ w_hi,
                                              const short* __restrict__ w_lo,
                                              const float* __restrict__ dinv,
                                              __half* __restrict__ h2) {
    __shared__ short xh[TM * LDR];
    __shared__ short xl[TM * LDR];
    __shared__ short wh[HIDDEN * LDR];
    __shared__ short wl[HIDDEN * LDR];
    const int t = threadIdx.x;
    const int lane = t & 63;
    const int wv = t >> 6;
    const int wr = wv >> 1, wc = wv & 1;   // 2x2 wave grid
    const int row0 = blockIdx.x * TM;

    f32x4 acc[4][4];
#pragma unroll
    for (int m = 0; m < 4; ++m)
#pragma unroll
        for (int n = 0; n < 4; ++n) acc[m][n] = (f32x4)0.f;

    // staging coords: x tile 128 rows x 32 fp32; thread -> (row, 16-elem half)
    const int rx = t >> 1, sx = t & 1;
    const int gxr = row0 + rx;
    const bool xok = (gxr < N_NODES);

    for (int k0 = 0; k0 < N_FEAT; k0 += KS) {
        // ---- stage x: fp32 -> bf16 hi/lo in registers -> LDS ----
        float4 f[4];
#pragma unroll
        for (int q = 0; q < 4; ++q) {
            f[q] = make_float4(0.f, 0.f, 0.f, 0.f);
            if (xok) f[q] = *(const float4*)&x[(size_t)gxr * N_FEAT + k0 + sx * 16 + q * 4];
        }
        unsigned hp[8], lp[8];
#pragma unroll
        for (int q = 0; q < 4; ++q) {
            float e0 = (&f[q].x)[0], e1 = (&f[q].x)[1], e2 = (&f[q].x)[2], e3 = (&f[q].x)[3];
            unsigned u0 = __float_as_uint(e0), u1 = __float_as_uint(e1);
            unsigned u2 = __float_as_uint(e2), u3 = __float_as_uint(e3);
            unsigned h0 = u0 & 0xFFFF0000u, h1 = u1 & 0xFFFF0000u;
            unsigned h2b = u2 & 0xFFFF0000u, h3 = u3 & 0xFFFF0000u;
            hp[q * 2 + 0] = (u0 >> 16) | h1;
            hp[q * 2 + 1] = (u2 >> 16) | h3;
            float r0 = e0 - __uint_as_float(h0), r1 = e1 - __uint_as_float(h1);
            float r2 = e2 - __uint_as_float(h2b), r3 = e3 - __uint_as_float(h3);
            lp[q * 2 + 0] = (__float_as_uint(r0) >> 16) | (__float_as_uint(r1) & 0xFFFF0000u);
            lp[q * 2 + 1] = (__float_as_uint(r2) >> 16) | (__float_as_uint(r3) & 0xFFFF0000u);
        }
        {
            int o = rx * LDR + sx * 16;  // shorts; 80B rows keep 16B alignment
            *(int4*)&xh[o]     = make_int4(hp[0], hp[1], hp[2], hp[3]);
            *(int4*)&xh[o + 8] = make_int4(hp[4], hp[5], hp[6], hp[7]);
            *(int4*)&xl[o]     = make_int4(lp[0], lp[1], lp[2], lp[3]);
            *(int4*)&xl[o + 8] = make_int4(lp[4], lp[5], lp[6], lp[7]);
        }
        // ---- stage W: bf16 direct copy (global -> reg -> LDS) ----
#pragma unroll
        for (int l = 0; l < 2; ++l) {
            int c = t + 256 * l;
            int rw = c >> 2, sl = c & 3;
            int4 a = *(const int4*)&w_hi[(size_t)rw * N_FEAT + k0 + sl * 8];
            *(int4*)&wh[rw * LDR + sl * 8] = a;
            int4 bq = *(const int4*)&w_lo[(size_t)rw * N_FEAT + k0 + sl * 8];
            *(int4*)&wl[rw * LDR + sl * 8] = bq;
        }
        __syncthreads();
        // ---- fragments ----
        const int fr = lane & 15, fs = lane >> 4;
        bf16x8 ah[4], al[4], bh[4], bl[4];
#pragma unroll
        for (int m = 0; m < 4; ++m) {
            int o = (wr * 64 + m * 16 + fr) * LDR + fs * 8;
            ah[m] = *(const bf16x8*)&xh[o];
            al[m] = *(const bf16x8*)&xl[o];
        }
#pragma unroll
        for (int n = 0; n < 4; ++n) {
            int o = (wc * 64 + n * 16 + fr) * LDR + fs * 8;
            bh[n] = *(const bf16x8*)&wh[o];
            bl[n] = *(const bf16x8*)&wl[o];
        }
        // ---- 3-pass MFMA ----
#pragma unroll
        for (int m = 0; m < 4; ++m)
#pragma unroll
            for (int n = 0; n < 4; ++n) {
                acc[m][n] = __builtin_amdgcn_mfma_f32_16x16x32_bf16(ah[m], bh[n], acc[m][n], 0, 0, 0);
                acc[m][n] = __builtin_amdgcn_mfma_f32_16x16x32_bf16(al[m], bh[n], acc[m][n], 0, 0, 0);
                acc[m][n] = __builtin_amdgcn_mfma_f32_16x16x32_bf16(ah[m], bl[n], acc[m][n], 0, 0, 0);
            }
        __syncthreads();
    }
    // ---- epilogue: h2 = fp16(acc * dinv) only ----
    // C/D layout: col = lane&15, row = (lane>>4)*4 + r
    const int cr = (lane >> 4) * 4, cc = lane & 15;
#pragma unroll
    for (int m = 0; m < 4; ++m) {
        int gr0 = row0 + wr * 64 + m * 16 + cr;
#pragma unroll
        for (int r = 0; r < 4; ++r) {
            int gr = gr0 + r;
            if (gr < N_NODES) {
                float d = dinv[gr];
#pragma unroll
                for (int n = 0; n < 4; ++n) {
                    int gc = wc * 64 + n * 16 + cc;
                    h2[(size_t)gr * HIDDEN + gc] = __float2half_rn(acc[m][n][r] * d);
                }
            }
        }
    }
}

// ---------------- gather-accumulate per node ----------------
// REVERT (round 12): token-faithful copy of the round-6 gather loop body --
// the only structure that empirically produced high-MLP codegen (VGPR 48,
// 80us). Clamped idx + wt[] predication; separate load loop; fmac-with-wt
// accumulate. Rounds 7-11 (sentinel/sched_barrier/liveness-asm/asm-burst)
// all collapsed to VGPR ~24 / MLP~1 / 95-100us. Only change vs round 6:
// base term computed from the sequential h2[n] read (self) + bias instead
// of an out[] RMW (keeps round 7's -51MB WRITE on the GEMM side).

__global__ __launch_bounds__(256) void k_gather(const int* __restrict__ row_ptr,
                                                const int* __restrict__ edge_src,
                                                const float* __restrict__ dinv,
                                                const __half* __restrict__ h2s,
                                                const float* __restrict__ b,
                                                const float* __restrict__ pa,
                                                float* __restrict__ out) {
    int n = (blockIdx.x * 256 + threadIdx.x) >> 6;
    int lane = threadIdx.x & 63;
    if (n >= N_NODES) return;
    int start = row_ptr[n], end = row_ptr[n + 1];
    float dn = dinv[n];
    const __half2* hp = (const __half2*)h2s;  // [N_NODES][64] half2
    // self term (sequential read of own row; h2 is pre-scaled by dinv[src])
    float2 base = __half22float2(hp[(unsigned)n * 64u + lane]);
    float2 acc = make_float2(0.f, 0.f);
    for (int e = start; e < end; e += 16) {
        int idx[16];
        float wt[16];
#pragma unroll
        for (int i = 0; i < 16; ++i) {
            int ee = e + i;
            int cl = (ee < end) ? ee : (end - 1);
            idx[i] = edge_src[cl];
            wt[i] = (ee < end) ? 1.f : 0.f;
        }
        __half2 v[16];
#pragma unroll
        for (int i = 0; i < 16; ++i) v[i] = hp[(unsigned)idx[i] * 64u + lane];
#pragma unroll
        for (int i = 0; i < 16; ++i) {
            float2 f = __half22float2(v[i]);
            acc.x += f.x * wt[i];
            acc.y += f.y * wt[i];
        }
    }
    float2 bb = *(const float2*)&b[lane * 2];
    float2 aa = *(const float2*)&pa[lane * 2];
    float2 r;
    r.x = dn * (base.x + acc.x) + bb.x;
    r.y = dn * (base.y + acc.y) + bb.y;
    r.x = r.x > 0.f ? r.x : r.x * aa.x;
    r.y = r.y > 0.f ? r.y : r.y * aa.y;
    *(float2*)&out[(size_t)n * HIDDEN + lane * 2] = r;
}

// ---------------- launch ----------------

extern "C" void kernel_launch(void* const* d_in, const int* in_sizes, int n_in,
                              void* d_out, int out_size, void* d_ws, size_t ws_size,
                              hipStream_t stream) {
    const float* x  = (const float*)d_in[0];
    const int*   ei = (const int*)d_in[1];   // [2, E] int32
    const float* W  = (const float*)d_in[2];
    const float* b  = (const float*)d_in[3];
    const float* pa = (const float*)d_in[4];
    float* out = (float*)d_out;

    const int* row = ei;            // sources
    const int* col = ei + N_EDGES;  // targets

    // ---- workspace layout (≈48 MB) ----
    char* w = (char*)d_ws;
    __half* h2      = (__half*)w;                                  // 25.6 MB
    int*   cnt      = (int*)(w + (size_t)(N_NODES + 1) * HIDDEN * 2);  // 400 KB
    int*   row_ptr  = cnt + N_NODES;                               // 400 KB + 8
    int*   bsum     = row_ptr + (N_NODES + 2);                     // 512 B
    int*   edge_src = bsum + 128;                                  // 6.4 MB
    float* dinv     = (float*)(edge_src + N_EDGES);                // 400 KB
    short* w_hi     = (short*)(dinv + N_NODES);                    // 64 KB
    short* w_lo     = w_hi + HIDDEN * N_FEAT;                      // 64 KB
    int*   gcur     = (int*)(w_lo + HIDDEN * N_FEAT);              // 1.6 KB
    int2*  recs     = (int2*)(((uintptr_t)(gcur + NBKT) + 15) & ~(uintptr_t)15);  // 14.4 MB

    k_zerog<<<(NBKT + 255) / 256, 256, 0, stream>>>(gcur);
    k_bin<<<NWG_BIN, 256, 0, stream>>>(row, col, gcur, recs);
    k_hist<<<NBKT, 256, 0, stream>>>(gcur, recs, cnt, dinv);
    k_scan1<<<NB, 256, 0, stream>>>(cnt, row_ptr, bsum);
    k_scan2<<<1, 64, 0, stream>>>(bsum, row_ptr);
    k_scan3<<<NB, 256, 0, stream>>>(row_ptr, bsum);
    k_slot2<<<NBKT, 256, 0, stream>>>(gcur, recs, row_ptr, edge_src);
    k_wconv<<<(HIDDEN * N_FEAT + 255) / 256, 256, 0, stream>>>(W, w_hi, w_lo);
    k_gemm<<<(N_NODES + TM - 1) / TM, 256, 0, stream>>>(x, w_hi, w_lo, dinv, h2);
    k_gather<<<(int)(((size_t)N_NODES * 64 + 255) / 256), 256, 0, stream>>>(
        row_ptr, edge_src, dinv, h2, b, pa, out);
}